// Round 4
// baseline (82.017 us; speedup 1.0000x reference)
//
#include <hip/hip_runtime.h>

#define BS 8192
#define D  128
#define TI 256              // i-rows per block (4 waves x 64 rows)
#define JCHUNK 512          // j's per block chunk
#define NJC (BS / JCHUNK)   // 16 (grid.y)
#define JPAN 64             // j-rows per panel (2 x 32-row tiles, 16 KB)
#define NP (JCHUNK / JPAN)  // 8 panels per chunk
#define PANBYTES (JPAN * D * 2)   // 16384

typedef __bf16 bf16x8 __attribute__((ext_vector_type(8)));
typedef float  f32x16 __attribute__((ext_vector_type(16)));

// async global->LDS, 16B per lane: LDS dest = (wave-uniform base) + lane*16,
// global src is per-lane (m97/m104 pattern, verified in R3)
__device__ __forceinline__ void gload_lds16(const void* g, void* l)
{
    __builtin_amdgcn_global_load_lds(
        (const __attribute__((address_space(1))) void*)g,
        (__attribute__((address_space(3))) void*)l, 16, 0, 0);
}

#define WAITVM(n) asm volatile("s_waitcnt vmcnt(" #n ")" ::: "memory")

// ---------------------------------------------------------------------------
// pack: feats -> fragment-major bf16 for BOTH anchor (Apack) and positive
// (Ppack), plus the fp32 row reductions (a_sq, psn = -p_sq/2, pd2). Layout
// (verified): piece ((tile*8 + s)*64 + lane) holds the 8 bf16 operand
// elements for MFMA lane `lane` at k-step s of 32-row tile `tile`:
//   row = tile*32 + (lane&31), k = s*16 + (lane>>5)*8 .. +8
// A 64-row panel is a CONTIGUOUS 16 KB block of Ppack — linear staging.
// ---------------------------------------------------------------------------
__global__ __launch_bounds__(256) void pack_kernel(
        const float* __restrict__ feats,
        __bf16* __restrict__ Apack, __bf16* __restrict__ Ppack,
        float* __restrict__ a_sq, float* __restrict__ psn,
        float* __restrict__ pd2)
{
    const int tile = blockIdx.x;          // 0..255
    const int tid  = threadIdx.x;
    const int r    = tid >> 3;            // row within tile, 0..31
    const int kb   = tid & 7;             // k-block = MFMA step s, 0..7
    const int row  = tile * 32 + r;

    const float4* asrc = (const float4*)(feats + (size_t)row * D + kb * 16);
    const float4* psrc = (const float4*)(feats + (size_t)(row + BS) * D + kb * 16);
    float4 a0 = asrc[0], a1 = asrc[1], a2 = asrc[2], a3 = asrc[3];
    float4 p0 = psrc[0], p1 = psrc[1], p2 = psrc[2], p3 = psrc[3];

    bf16x8 alo, ahi, plo, phi;
    alo[0]=(__bf16)a0.x; alo[1]=(__bf16)a0.y; alo[2]=(__bf16)a0.z; alo[3]=(__bf16)a0.w;
    alo[4]=(__bf16)a1.x; alo[5]=(__bf16)a1.y; alo[6]=(__bf16)a1.z; alo[7]=(__bf16)a1.w;
    ahi[0]=(__bf16)a2.x; ahi[1]=(__bf16)a2.y; ahi[2]=(__bf16)a2.z; ahi[3]=(__bf16)a2.w;
    ahi[4]=(__bf16)a3.x; ahi[5]=(__bf16)a3.y; ahi[6]=(__bf16)a3.z; ahi[7]=(__bf16)a3.w;
    plo[0]=(__bf16)p0.x; plo[1]=(__bf16)p0.y; plo[2]=(__bf16)p0.z; plo[3]=(__bf16)p0.w;
    plo[4]=(__bf16)p1.x; plo[5]=(__bf16)p1.y; plo[6]=(__bf16)p1.z; plo[7]=(__bf16)p1.w;
    phi[0]=(__bf16)p2.x; phi[1]=(__bf16)p2.y; phi[2]=(__bf16)p2.z; phi[3]=(__bf16)p2.w;
    phi[4]=(__bf16)p3.x; phi[5]=(__bf16)p3.y; phi[6]=(__bf16)p3.z; phi[7]=(__bf16)p3.w;

    const size_t pb = ((size_t)tile * 8 + kb) * 64;
    ((bf16x8*)Apack)[pb + r]      = alo;
    ((bf16x8*)Apack)[pb + 32 + r] = ahi;
    ((bf16x8*)Ppack)[pb + r]      = plo;
    ((bf16x8*)Ppack)[pb + 32 + r] = phi;

    float sa = a0.x*a0.x + a0.y*a0.y + a0.z*a0.z + a0.w*a0.w
             + a1.x*a1.x + a1.y*a1.y + a1.z*a1.z + a1.w*a1.w
             + a2.x*a2.x + a2.y*a2.y + a2.z*a2.z + a2.w*a2.w
             + a3.x*a3.x + a3.y*a3.y + a3.z*a3.z + a3.w*a3.w;
    float sp = p0.x*p0.x + p0.y*p0.y + p0.z*p0.z + p0.w*p0.w
             + p1.x*p1.x + p1.y*p1.y + p1.z*p1.z + p1.w*p1.w
             + p2.x*p2.x + p2.y*p2.y + p2.z*p2.z + p2.w*p2.w
             + p3.x*p3.x + p3.y*p3.y + p3.z*p3.z + p3.w*p3.w;
    float d;
    float sd = 0.0f;
    d = a0.x-p0.x; sd += d*d;  d = a0.y-p0.y; sd += d*d;
    d = a0.z-p0.z; sd += d*d;  d = a0.w-p0.w; sd += d*d;
    d = a1.x-p1.x; sd += d*d;  d = a1.y-p1.y; sd += d*d;
    d = a1.z-p1.z; sd += d*d;  d = a1.w-p1.w; sd += d*d;
    d = a2.x-p2.x; sd += d*d;  d = a2.y-p2.y; sd += d*d;
    d = a2.z-p2.z; sd += d*d;  d = a2.w-p2.w; sd += d*d;
    d = a3.x-p3.x; sd += d*d;  d = a3.y-p3.y; sd += d*d;
    d = a3.z-p3.z; sd += d*d;  d = a3.w-p3.w; sd += d*d;

    #pragma unroll
    for (int off = 1; off <= 4; off <<= 1) {
        sa += __shfl_xor(sa, off, 64);
        sp += __shfl_xor(sp, off, 64);
        sd += __shfl_xor(sd, off, 64);
    }
    if (kb == 0) { a_sq[row] = sa; psn[row] = -0.5f * sp; pd2[row] = sd; }
}

// ---------------------------------------------------------------------------
// max kernel, counted-vmcnt deep pipeline (T3+T4 port).
//
// R0/R3 post-mortem: both the register pipeline and the LDS 2-phase land at
// ~30 us = ~570 TF = the guide's measured 2-phase structural ceiling
// (m230/m233/m248). The cost is the per-panel vmcnt(0) drain inside
// __syncthreads: every panel waits for its OWN freshly-issued prefetch.
// Fix (m218: counted-vs-drain0 = +38-73%): 4 LDS buffers, depth-2
// prefetch, ONE raw s_barrier per panel, counted s_waitcnt vmcnt(8) —
// panel t's loads drain while t+1/t+2's 8 loads stay in flight across
// barriers (~2 panel-bodies of cover >> L2 latency).
//
// Race safety (one barrier/iter): skew between waves <= 1 iteration.
// stage(t+2) writes buf[(t+2)&3], last READ at iter t-2; every wave
// passed iter t-1's barrier, which is after its iter t-2 body (MFMAs
// consumed the ds_reads -> data drained). 4 buffers x 16 KB = 64 KB,
// 2 blocks/CU = 128 KB < 160.
//
// Also: the 16 psn values (acc-init constants) were a per-panel ~300-cyc
// L2 latency on the critical path — hoisted to prologue registers.
// T5 setprio wraps the MFMA cluster (pays on phase-split schedules).
//
// mfma_f32_32x32x16_bf16 C/D layout (HW-verified, learn_hip m74/m101):
//   col = lane&31, row = (reg&3) + 8*(reg>>2) + 4*(lane>>5)
// ---------------------------------------------------------------------------
__global__ __launch_bounds__(256, 2) void max_kernel(
        const __bf16* __restrict__ Apack, const __bf16* __restrict__ Ppack,
        const float* __restrict__ psn, float* __restrict__ partmax)
{
    __shared__ __align__(16) char sB[4 * PANBYTES];   // 64 KB, 4 panel bufs

    const int tid  = threadIdx.x;               // 0..255
    const int wave = tid >> 6;                  // 0..3
    const int lane = tid & 63;
    const int l31  = lane & 31;
    const int half = lane >> 5;

    const int i0    = blockIdx.x * TI + wave * 64;   // wave's 64 anchor rows
    const int itile = i0 >> 5;
    const int jbase = blockIdx.y * JCHUNK;
    const int tile0 = jbase >> 5;

    // A fragments (2 tiles/wave), coalesced 1 KB wave-loads from Apack
    bf16x8 afA[8], afB[8];
    {
        const bf16x8* ap = (const bf16x8*)Apack;
        #pragma unroll
        for (int s = 0; s < 8; ++s) {
            afA[s] = ap[((size_t)itile * 8 + s) * 64 + lane];
            afB[s] = ap[((size_t)(itile + 1) * 8 + s) * 64 + lane];
        }
    }

    // acc-init constants for all 16 j-tiles of this chunk, hoisted out of
    // the loop (was a per-panel L2-latency load on the critical path)
    float ci[16];
    #pragma unroll
    for (int k = 0; k < 16; ++k) ci[k] = psn[jbase + k * 32 + l31];

    float rmaxA[16], rmaxB[16];
    #pragma unroll
    for (int r = 0; r < 16; ++r) { rmaxA[r] = -3.0e38f; rmaxB[r] = -3.0e38f; }

    // panel t = contiguous 16 KB at Ppack byte offset (tile0>>1 + t)*16384.
    // Each wave stages its own 4 KB slice (4 x 1 KB gload_lds issues);
    // global src includes wave*4096 + lane*16, LDS base is wave-uniform.
    const char* gpan = (const char*)Ppack + (size_t)(tile0 >> 1) * PANBYTES
                     + wave * 4096 + lane * 16;

    #define STAGE(p, buf)                                                  \
        do {                                                               \
            const char* g_ = gpan + (size_t)(p) * PANBYTES;                \
            char* l_ = sB + (buf) * PANBYTES + wave * 4096;                \
            gload_lds16(g_,        l_);                                    \
            gload_lds16(g_ + 1024, l_ + 1024);                             \
            gload_lds16(g_ + 2048, l_ + 2048);                             \
            gload_lds16(g_ + 3072, l_ + 3072);                             \
        } while (0)

    // prologue: panels 0 and 1 in flight
    STAGE(0, 0);
    STAGE(1, 1);

    #pragma unroll
    for (int t = 0; t < NP; ++t) {
        if (t + 2 < NP) STAGE(t + 2, (t + 2) & 3);

        // counted wait: panel t's 4 loads done, t+1/t+2's (8) stay in flight
        if (t < NP - 2)       WAITVM(8);
        else if (t == NP - 2) WAITVM(4);
        else                  WAITVM(0);
        __builtin_amdgcn_sched_barrier(0);
        __builtin_amdgcn_s_barrier();       // all waves' panel-t slices in
        __builtin_amdgcn_sched_barrier(0);

        const char* pbase = sB + (t & 3) * PANBYTES;
        #pragma unroll
        for (int bt = 0; bt < 2; ++bt) {
            const bf16x8* lp =
                (const bf16x8*)(pbase + bt * 8192 + (size_t)lane * 16);
            bf16x8 b[8];
            #pragma unroll
            for (int s = 0; s < 8; ++s) b[s] = lp[s * 64];

            const float cv = ci[2 * t + bt];
            f32x16 acc0, acc1;
            #pragma unroll
            for (int r = 0; r < 16; ++r) { acc0[r] = cv; acc1[r] = cv; }

            __builtin_amdgcn_s_setprio(1);
            #pragma unroll
            for (int s = 0; s < 8; ++s) {
                acc0 = __builtin_amdgcn_mfma_f32_32x32x16_bf16(afA[s], b[s],
                                                               acc0, 0, 0, 0);
                acc1 = __builtin_amdgcn_mfma_f32_32x32x16_bf16(afB[s], b[s],
                                                               acc1, 0, 0, 0);
            }
            __builtin_amdgcn_s_setprio(0);

            #pragma unroll
            for (int r = 0; r < 16; ++r) {
                rmaxA[r] = fmaxf(rmaxA[r], acc0[r]);
                rmaxB[r] = fmaxf(rmaxB[r], acc1[r]);
            }
        }
    }
    #undef STAGE

    // max across the 32 columns (off<=16 stays within each 32-lane half)
    #pragma unroll
    for (int r = 0; r < 16; ++r) {
        float vA = rmaxA[r], vB = rmaxB[r];
        #pragma unroll
        for (int off = 1; off <= 16; off <<= 1) {
            vA = fmaxf(vA, __shfl_xor(vA, off, 64));
            vB = fmaxf(vB, __shfl_xor(vB, off, 64));
        }
        rmaxA[r] = vA; rmaxB[r] = vB;
    }
    if (l31 == 0) {
        float* dst = partmax + (size_t)blockIdx.y * BS + i0;
        #pragma unroll
        for (int r = 0; r < 16; ++r) {
            int row = (r & 3) + 8 * (r >> 2) + 4 * half;
            dst[row]      = rmaxA[r];
            dst[row + 32] = rmaxB[r];
        }
    }
}

// ---------------------------------------------------------------------------
// fin stage 1: 32 blocks x 256 threads; thread handles exactly one i.
// min_j d2 = a_sq[i] - 2 * max_c partmax[c][i]
// ---------------------------------------------------------------------------
__global__ __launch_bounds__(256) void fin1_kernel(
        const float* __restrict__ partmax, const float* __restrict__ a_sq,
        const float* __restrict__ pd2, float* __restrict__ bsum)
{
    __shared__ float ssum[4];
    const int t = threadIdx.x;
    const int i = blockIdx.x * 256 + t;

    float m = -3.0e38f;
    #pragma unroll
    for (int c = 0; c < NJC; ++c)
        m = fmaxf(m, partmax[c * BS + i]);
    float negd = sqrtf(fmaxf(fmaf(-2.0f, m, a_sq[i]), 0.0f));
    float posd = sqrtf(pd2[i]);
    float sum = fmaxf(posd - negd + 1.0f, 0.0f);

    #pragma unroll
    for (int off = 32; off >= 1; off >>= 1) sum += __shfl_xor(sum, off, 64);
    if ((t & 63) == 0) ssum[t >> 6] = sum;
    __syncthreads();
    if (t == 0)
        bsum[blockIdx.x] = ssum[0] + ssum[1] + ssum[2] + ssum[3];
}

// fin stage 2: one wave sums the 32 block partials.
__global__ __launch_bounds__(64) void fin2_kernel(
        const float* __restrict__ bsum, float* __restrict__ out)
{
    const int t = threadIdx.x;
    float v = (t < 32) ? bsum[t] : 0.0f;
    #pragma unroll
    for (int off = 32; off >= 1; off >>= 1) v += __shfl_xor(v, off, 64);
    if (t == 0) out[0] = v / (float)BS;
}

// ---------------------------------------------------------------------------
extern "C" void kernel_launch(void* const* d_in, const int* in_sizes, int n_in,
                              void* d_out, int out_size, void* d_ws,
                              size_t ws_size, hipStream_t stream)
{
    const float* feats = (const float*)d_in[0];

    char* ws = (char*)d_ws;
    __bf16* Apack = (__bf16*)ws;  ws += (size_t)BS * D * 2;   // 2 MB
    __bf16* Ppack = (__bf16*)ws;  ws += (size_t)BS * D * 2;   // 2 MB
    float* a_sq   = (float*)ws;   ws += (size_t)BS * 4;
    float* psn    = (float*)ws;   ws += (size_t)BS * 4;
    float* pd2    = (float*)ws;   ws += (size_t)BS * 4;
    float* partmax = (float*)ws;  ws += (size_t)NJC * BS * 4; // 512 KB
    float* bsum   = (float*)ws;   ws += 32 * 4;

    pack_kernel<<<BS / 32, 256, 0, stream>>>(feats, Apack, Ppack,
                                             a_sq, psn, pd2);
    dim3 grid(BS / TI, NJC);
    max_kernel<<<grid, 256, 0, stream>>>(Apack, Ppack, psn, partmax);
    fin1_kernel<<<BS / 256, 256, 0, stream>>>(partmax, a_sq, pd2, bsum);
    fin2_kernel<<<1, 64, 0, stream>>>(bsum, (float*)d_out);
}

// Round 5
// 81.718 us; speedup vs baseline: 1.0037x; 1.0037x over previous
//
#include <hip/hip_runtime.h>

#define BS 8192
#define D  128
#define TI 256              // i-rows per block (4 waves x 64 rows)
#define JCHUNK 512          // j's per block chunk
#define NJC (BS / JCHUNK)   // 16 (grid.y)
#define JPAN 64             // j-rows per panel (2 x 32-row tiles, 16 KB)
#define NP (JCHUNK / JPAN)  // 8 panels per chunk
#define PANBYTES (JPAN * D * 2)   // 16384

typedef __bf16 bf16x8 __attribute__((ext_vector_type(8)));
typedef float  f32x16 __attribute__((ext_vector_type(16)));

// async global->LDS, 16B per lane: LDS dest = (wave-uniform base) + lane*16,
// global src is per-lane (m97/m104 pattern, verified in R3/R4)
__device__ __forceinline__ void gload_lds16(const void* g, void* l)
{
    __builtin_amdgcn_global_load_lds(
        (const __attribute__((address_space(1))) void*)g,
        (__attribute__((address_space(3))) void*)l, 16, 0, 0);
}

#define WAITVM(n) asm volatile("s_waitcnt vmcnt(" #n ")" ::: "memory")

// ---------------------------------------------------------------------------
// pack: feats -> fragment-major bf16 for BOTH anchor (Apack) and positive
// (Ppack), plus the fp32 row reductions (a_sq, psn = -p_sq/2, pd2). Layout
// (verified): piece ((tile*8 + s)*64 + lane) holds the 8 bf16 operand
// elements for MFMA lane `lane` at k-step s of 32-row tile `tile`:
//   row = tile*32 + (lane&31), k = s*16 + (lane>>5)*8 .. +8
// A 64-row panel is a CONTIGUOUS 16 KB block of Ppack — linear staging.
// ---------------------------------------------------------------------------
__global__ __launch_bounds__(256) void pack_kernel(
        const float* __restrict__ feats,
        __bf16* __restrict__ Apack, __bf16* __restrict__ Ppack,
        float* __restrict__ a_sq, float* __restrict__ psn,
        float* __restrict__ pd2)
{
    const int tile = blockIdx.x;          // 0..255
    const int tid  = threadIdx.x;
    const int r    = tid >> 3;            // row within tile, 0..31
    const int kb   = tid & 7;             // k-block = MFMA step s, 0..7
    const int row  = tile * 32 + r;

    const float4* asrc = (const float4*)(feats + (size_t)row * D + kb * 16);
    const float4* psrc = (const float4*)(feats + (size_t)(row + BS) * D + kb * 16);
    float4 a0 = asrc[0], a1 = asrc[1], a2 = asrc[2], a3 = asrc[3];
    float4 p0 = psrc[0], p1 = psrc[1], p2 = psrc[2], p3 = psrc[3];

    bf16x8 alo, ahi, plo, phi;
    alo[0]=(__bf16)a0.x; alo[1]=(__bf16)a0.y; alo[2]=(__bf16)a0.z; alo[3]=(__bf16)a0.w;
    alo[4]=(__bf16)a1.x; alo[5]=(__bf16)a1.y; alo[6]=(__bf16)a1.z; alo[7]=(__bf16)a1.w;
    ahi[0]=(__bf16)a2.x; ahi[1]=(__bf16)a2.y; ahi[2]=(__bf16)a2.z; ahi[3]=(__bf16)a2.w;
    ahi[4]=(__bf16)a3.x; ahi[5]=(__bf16)a3.y; ahi[6]=(__bf16)a3.z; ahi[7]=(__bf16)a3.w;
    plo[0]=(__bf16)p0.x; plo[1]=(__bf16)p0.y; plo[2]=(__bf16)p0.z; plo[3]=(__bf16)p0.w;
    plo[4]=(__bf16)p1.x; plo[5]=(__bf16)p1.y; plo[6]=(__bf16)p1.z; plo[7]=(__bf16)p1.w;
    phi[0]=(__bf16)p2.x; phi[1]=(__bf16)p2.y; phi[2]=(__bf16)p2.z; phi[3]=(__bf16)p2.w;
    phi[4]=(__bf16)p3.x; phi[5]=(__bf16)p3.y; phi[6]=(__bf16)p3.z; phi[7]=(__bf16)p3.w;

    const size_t pb = ((size_t)tile * 8 + kb) * 64;
    ((bf16x8*)Apack)[pb + r]      = alo;
    ((bf16x8*)Apack)[pb + 32 + r] = ahi;
    ((bf16x8*)Ppack)[pb + r]      = plo;
    ((bf16x8*)Ppack)[pb + 32 + r] = phi;

    float sa = a0.x*a0.x + a0.y*a0.y + a0.z*a0.z + a0.w*a0.w
             + a1.x*a1.x + a1.y*a1.y + a1.z*a1.z + a1.w*a1.w
             + a2.x*a2.x + a2.y*a2.y + a2.z*a2.z + a2.w*a2.w
             + a3.x*a3.x + a3.y*a3.y + a3.z*a3.z + a3.w*a3.w;
    float sp = p0.x*p0.x + p0.y*p0.y + p0.z*p0.z + p0.w*p0.w
             + p1.x*p1.x + p1.y*p1.y + p1.z*p1.z + p1.w*p1.w
             + p2.x*p2.x + p2.y*p2.y + p2.z*p2.z + p2.w*p2.w
             + p3.x*p3.x + p3.y*p3.y + p3.z*p3.z + p3.w*p3.w;
    float d;
    float sd = 0.0f;
    d = a0.x-p0.x; sd += d*d;  d = a0.y-p0.y; sd += d*d;
    d = a0.z-p0.z; sd += d*d;  d = a0.w-p0.w; sd += d*d;
    d = a1.x-p1.x; sd += d*d;  d = a1.y-p1.y; sd += d*d;
    d = a1.z-p1.z; sd += d*d;  d = a1.w-p1.w; sd += d*d;
    d = a2.x-p2.x; sd += d*d;  d = a2.y-p2.y; sd += d*d;
    d = a2.z-p2.z; sd += d*d;  d = a2.w-p2.w; sd += d*d;
    d = a3.x-p3.x; sd += d*d;  d = a3.y-p3.y; sd += d*d;
    d = a3.z-p3.z; sd += d*d;  d = a3.w-p3.w; sd += d*d;

    #pragma unroll
    for (int off = 1; off <= 4; off <<= 1) {
        sa += __shfl_xor(sa, off, 64);
        sp += __shfl_xor(sp, off, 64);
        sd += __shfl_xor(sd, off, 64);
    }
    if (kb == 0) { a_sq[row] = sa; psn[row] = -0.5f * sp; pd2[row] = sd; }
}

// ---------------------------------------------------------------------------
// max kernel: counted-vmcnt HBM->LDS pipeline (R4) + rolling one-body-ahead
// LDS->register pipeline (NEW).
//
// R0/R3/R4 post-mortem: three different panel-level schedules all hit
// ~31 us (~4.5x the 7 us pipe floor). The invariant serial chain was
// per-body: barrier -> 8 ds_read_b128 (~150 cyc) -> lgkm wait -> 32 movs
// -> 16 MFMA, repeated 16x per wave with only 2 waves/SIMD to cover it
// (8 waves/CU is register-locked: af+acc+rmax >= 128 VGPR, m69 bands).
//
// Fix: WAITVM(4) so the barrier at iter t publishes panels t AND t+1.
// Then body n+1's ds_reads issue DURING body n's MFMAs (rolling bcur/bnxt
// register pair, all compile-time indices). The lgkm wait before body
// n+1's MFMAs refers to reads issued ~500 cyc earlier -> satisfied ->
// critical path = MFMA issue + fmax only.
//
// Race safety (skew < 1 iter, one barrier/iter, 4-buffer ring):
//  - STAGE(t+2) overwrites buf[(t-2)&3]; last LDS reads of panel t-2
//    happen in iter t-2 (rolling reads of panel q end in iter q), behind
//    barrier t-1 which every wave passed. Safe.
//  - body 2t+2 (panel t+1) is read only after iter t's barrier, which
//    published panel t+1 via WAITVM(4). Safe.
//  - vmcnt FIFO: steady state each iter has {panel t+1, t+2} = 8
//    outstanding after STAGE; WAITVM(4) drains panel t+1 exactly.
//
// mfma_f32_32x32x16_bf16 C/D layout (HW-verified, learn_hip m74/m101):
//   col = lane&31, row = (reg&3) + 8*(reg>>2) + 4*(lane>>5)
// ---------------------------------------------------------------------------
__global__ __launch_bounds__(256, 2) void max_kernel(
        const __bf16* __restrict__ Apack, const __bf16* __restrict__ Ppack,
        const float* __restrict__ psn, float* __restrict__ partmax)
{
    __shared__ __align__(16) char sB[4 * PANBYTES];   // 64 KB, 4 panel bufs

    const int tid  = threadIdx.x;               // 0..255
    const int wave = tid >> 6;                  // 0..3
    const int lane = tid & 63;
    const int l31  = lane & 31;
    const int half = lane >> 5;

    const int i0    = blockIdx.x * TI + wave * 64;   // wave's 64 anchor rows
    const int itile = i0 >> 5;
    const int jbase = blockIdx.y * JCHUNK;
    const int tile0 = jbase >> 5;

    // A fragments (2 tiles/wave), coalesced 1 KB wave-loads from Apack
    bf16x8 afA[8], afB[8];
    {
        const bf16x8* ap = (const bf16x8*)Apack;
        #pragma unroll
        for (int s = 0; s < 8; ++s) {
            afA[s] = ap[((size_t)itile * 8 + s) * 64 + lane];
            afB[s] = ap[((size_t)(itile + 1) * 8 + s) * 64 + lane];
        }
    }

    // acc-init constants for all 16 j-tiles of this chunk (hoisted)
    float ci[16];
    #pragma unroll
    for (int k = 0; k < 16; ++k) ci[k] = psn[jbase + k * 32 + l31];

    float rmaxA[16], rmaxB[16];
    #pragma unroll
    for (int r = 0; r < 16; ++r) { rmaxA[r] = -3.0e38f; rmaxB[r] = -3.0e38f; }

    // panel t = contiguous 16 KB at Ppack byte offset (tile0>>1 + t)*16384.
    // Each wave stages its own 4 KB slice (4 x 1 KB gload_lds issues).
    const char* gpan = (const char*)Ppack + (size_t)(tile0 >> 1) * PANBYTES
                     + wave * 4096 + lane * 16;

    #define STAGE(p, buf)                                                  \
        do {                                                               \
            const char* g_ = gpan + (size_t)(p) * PANBYTES;                \
            char* l_ = sB + (buf) * PANBYTES + wave * 4096;                \
            gload_lds16(g_,        l_);                                    \
            gload_lds16(g_ + 1024, l_ + 1024);                             \
            gload_lds16(g_ + 2048, l_ + 2048);                             \
            gload_lds16(g_ + 3072, l_ + 3072);                             \
        } while (0)

    // LDS address of body n (j-tile n): buf (n>>1)&3, half (n&1)
    #define BODY_PTR(n) ((const bf16x8*)(sB + (((n) >> 1) & 3) * PANBYTES   \
                          + ((n) & 1) * 8192 + (size_t)lane * 16))

    // one j-tile body: 16 MFMAs on (afA,afB) x b, fmax into rmax
    #define BODY(breg, cv)                                                 \
        do {                                                               \
            f32x16 acc0, acc1;                                             \
            _Pragma("unroll")                                              \
            for (int r = 0; r < 16; ++r) { acc0[r] = (cv); acc1[r] = (cv); } \
            __builtin_amdgcn_s_setprio(1);                                 \
            _Pragma("unroll")                                              \
            for (int s = 0; s < 8; ++s) {                                  \
                acc0 = __builtin_amdgcn_mfma_f32_32x32x16_bf16(afA[s],     \
                        breg[s], acc0, 0, 0, 0);                           \
                acc1 = __builtin_amdgcn_mfma_f32_32x32x16_bf16(afB[s],     \
                        breg[s], acc1, 0, 0, 0);                           \
            }                                                              \
            __builtin_amdgcn_s_setprio(0);                                 \
            _Pragma("unroll")                                              \
            for (int r = 0; r < 16; ++r) {                                 \
                rmaxA[r] = fmaxf(rmaxA[r], acc0[r]);                       \
                rmaxB[r] = fmaxf(rmaxB[r], acc1[r]);                       \
            }                                                              \
        } while (0)

    // prologue: panels 0 and 1 in flight
    STAGE(0, 0);
    STAGE(1, 1);

    bf16x8 bcur[8], bnxt[8];

    #pragma unroll
    for (int t = 0; t < NP; ++t) {
        if (t + 2 < NP) STAGE(t + 2, (t + 2) & 3);

        // publish panel t+1 (and panel t, drained one iter earlier):
        // steady state outstanding = {t+1, t+2} = 8 -> drain to 4.
        if (t < NP - 2) WAITVM(4);
        else            WAITVM(0);
        __builtin_amdgcn_sched_barrier(0);
        __builtin_amdgcn_s_barrier();
        __builtin_amdgcn_sched_barrier(0);

        if (t == 0) {              // one-time: read body 0 (panel 0 resident)
            const bf16x8* lp = BODY_PTR(0);
            #pragma unroll
            for (int s = 0; s < 8; ++s) bcur[s] = lp[s * 64];
        }

        // body 2t (regs loaded last iter / just above); roll in body 2t+1
        {
            const bf16x8* lp = BODY_PTR(2 * t + 1);   // panel t: resident
            #pragma unroll
            for (int s = 0; s < 8; ++s) bnxt[s] = lp[s * 64];
            BODY(bcur, ci[2 * t]);
        }
        // body 2t+1; roll in body 2t+2 (panel t+1: published this iter)
        {
            if (2 * t + 2 < 2 * NP) {
                const bf16x8* lp = BODY_PTR(2 * t + 2);
                #pragma unroll
                for (int s = 0; s < 8; ++s) bcur[s] = lp[s * 64];
            }
            BODY(bnxt, ci[2 * t + 1]);
        }
    }
    #undef STAGE
    #undef BODY_PTR
    #undef BODY

    // max across the 32 columns (off<=16 stays within each 32-lane half)
    #pragma unroll
    for (int r = 0; r < 16; ++r) {
        float vA = rmaxA[r], vB = rmaxB[r];
        #pragma unroll
        for (int off = 1; off <= 16; off <<= 1) {
            vA = fmaxf(vA, __shfl_xor(vA, off, 64));
            vB = fmaxf(vB, __shfl_xor(vB, off, 64));
        }
        rmaxA[r] = vA; rmaxB[r] = vB;
    }
    if (l31 == 0) {
        float* dst = partmax + (size_t)blockIdx.y * BS + i0;
        #pragma unroll
        for (int r = 0; r < 16; ++r) {
            int row = (r & 3) + 8 * (r >> 2) + 4 * half;
            dst[row]      = rmaxA[r];
            dst[row + 32] = rmaxB[r];
        }
    }
}

// ---------------------------------------------------------------------------
// fin stage 1: 32 blocks x 256 threads; thread handles exactly one i.
// min_j d2 = a_sq[i] - 2 * max_c partmax[c][i]
// ---------------------------------------------------------------------------
__global__ __launch_bounds__(256) void fin1_kernel(
        const float* __restrict__ partmax, const float* __restrict__ a_sq,
        const float* __restrict__ pd2, float* __restrict__ bsum)
{
    __shared__ float ssum[4];
    const int t = threadIdx.x;
    const int i = blockIdx.x * 256 + t;

    float m = -3.0e38f;
    #pragma unroll
    for (int c = 0; c < NJC; ++c)
        m = fmaxf(m, partmax[c * BS + i]);
    float negd = sqrtf(fmaxf(fmaf(-2.0f, m, a_sq[i]), 0.0f));
    float posd = sqrtf(pd2[i]);
    float sum = fmaxf(posd - negd + 1.0f, 0.0f);

    #pragma unroll
    for (int off = 32; off >= 1; off >>= 1) sum += __shfl_xor(sum, off, 64);
    if ((t & 63) == 0) ssum[t >> 6] = sum;
    __syncthreads();
    if (t == 0)
        bsum[blockIdx.x] = ssum[0] + ssum[1] + ssum[2] + ssum[3];
}

// fin stage 2: one wave sums the 32 block partials.
__global__ __launch_bounds__(64) void fin2_kernel(
        const float* __restrict__ bsum, float* __restrict__ out)
{
    const int t = threadIdx.x;
    float v = (t < 32) ? bsum[t] : 0.0f;
    #pragma unroll
    for (int off = 32; off >= 1; off >>= 1) v += __shfl_xor(v, off, 64);
    if (t == 0) out[0] = v / (float)BS;
}

// ---------------------------------------------------------------------------
extern "C" void kernel_launch(void* const* d_in, const int* in_sizes, int n_in,
                              void* d_out, int out_size, void* d_ws,
                              size_t ws_size, hipStream_t stream)
{
    const float* feats = (const float*)d_in[0];

    char* ws = (char*)d_ws;
    __bf16* Apack = (__bf16*)ws;  ws += (size_t)BS * D * 2;   // 2 MB
    __bf16* Ppack = (__bf16*)ws;  ws += (size_t)BS * D * 2;   // 2 MB
    float* a_sq   = (float*)ws;   ws += (size_t)BS * 4;
    float* psn    = (float*)ws;   ws += (size_t)BS * 4;
    float* pd2    = (float*)ws;   ws += (size_t)BS * 4;
    float* partmax = (float*)ws;  ws += (size_t)NJC * BS * 4; // 512 KB
    float* bsum   = (float*)ws;   ws += 32 * 4;

    pack_kernel<<<BS / 32, 256, 0, stream>>>(feats, Apack, Ppack,
                                             a_sq, psn, pd2);
    dim3 grid(BS / TI, NJC);
    max_kernel<<<grid, 256, 0, stream>>>(Apack, Ppack, psn, partmax);
    fin1_kernel<<<BS / 256, 256, 0, stream>>>(partmax, a_sq, pd2, bsum);
    fin2_kernel<<<1, 64, 0, stream>>>(bsum, (float*)d_out);
}